// Round 19
// baseline (192.499 us; speedup 1.0000x reference)
//
#include <hip/hip_runtime.h>

#define NSEQ   16
#define KVH    8
#define NG     4      // query heads per kv head
#define HD     128
#define BS     16
#define MAXB   256
#define PART   256    // tokens per work item (4 waves x 64)
#define NPART  16
#define NITEMS (NSEQ * KVH * NPART)   // 2048 work items
#define NPAIRS (NSEQ * KVH)           // 128
#define WPT    64     // tokens per wave
#define PSTRIDE 520   // floats per partition record: o[512], l[4], m, pad
#define REC_BYTES ((size_t)NITEMS * PSTRIDE * 4)
#define SCALE_F 0.08838834764831845f
#define NWORKERS 1024

typedef float vf4 __attribute__((ext_vector_type(4)));
__device__ __forceinline__ float4 ldnt4f(const float* p) {
    vf4 v = __builtin_nontemporal_load((const vf4*)p);
    return make_float4(v[0], v[1], v[2], v[3]);
}

// agent-scope (device-coherent) float load — r16-proven for cross-XCD record
// reads (Guideline 16).
__device__ __forceinline__ float cohld(const float* p) {
    return __hip_atomic_load(p, __ATOMIC_RELAXED, __HIP_MEMORY_SCOPE_AGENT);
}

// FUSED kernel, manual end-barrier (no cooperative launch — r18's coop launch
// failed validation and never ran).
// Phase 1: r17's body verbatim (block work stealing, two-barrier grab, 4
//   independent waves, wave-local softmax, contiguous-V PV, 25% nt).
// End protocol (deadlock-free WITHOUT co-residency): every block, after the
//   steal counter drains: __threadfence (release) + atomicAdd(done,1), then
//   exits -- except blocks 0..127 which spin on done==NWORKERS (acquire,
//   agent scope) and reduce their pair with cohld reads. Workers never wait
//   on anyone -> done always reaches NWORKERS -> no deadlock. One fence per
//   BLOCK (vs r16's per-item) and all 128 reducers run in parallel.
__global__ __launch_bounds__(256) void pa_fused_kernel(
    const float* __restrict__ query,
    const float* __restrict__ key,
    const float* __restrict__ value,
    const float* __restrict__ key_cache,
    const float* __restrict__ value_cache,
    const int*   __restrict__ block_tables,
    const int*   __restrict__ context_lens,
    float*       __restrict__ ws,
    unsigned int* __restrict__ counter,    // [0]=steal, [1]=done
    float*       __restrict__ out)
{
    __shared__ float p_lds[4][NG][WPT];   // per-wave probabilities
    __shared__ float o_lds[4][NG * HD];   // per-wave partial outputs
    __shared__ float ml_lds[4][8];        // per-wave m, l[4]
    __shared__ int   item_s;

    const int tid  = threadIdx.x;
    const int wv   = tid >> 6;
    const int lane = tid & 63;

    for (;;) {
        if (tid == 0) item_s = (int)atomicAdd(&counter[0], 1u);
        __syncthreads();                  // B1: item_s write visible
        const int item = item_s;
        __syncthreads();                  // B2: all have read; safe to overwrite later
        if (item >= NITEMS) break;        // drained -> end protocol

        const int p   = item & (NPART - 1);
        const int kvh = (item >> 4) & (KVH - 1);
        const int s   = item >> 7;
        const int ctx = context_lens[s];
        const int t0  = p * PART;
        if (t0 >= ctx) continue;          // barrier-safe skip

        const bool ntp = ((p & 3) == 3);  // wave-uniform nt decision (25% of items)

        const int tw0  = t0 + wv * WPT;
        const bool wact = (tw0 < ctx);

        const float* q = query + ((size_t)s * KVH + kvh) * (NG * HD);

        float m_w = -1e30f;
        float l_w[NG] = {0.f, 0.f, 0.f, 0.f};

        if (wact) {
            // ---- QK: one token per lane ----
            const int t  = tw0 + lane;                     // < 4096: in-bounds
            const int bt = block_tables[s * MAXB + (t >> 4)];
            const float* kb = key_cache + (size_t)bt * (KVH * HD * BS)
                                        + (size_t)kvh * (HD * BS) + (t & 15) * 8;

            float sc[NG] = {0.f, 0.f, 0.f, 0.f};
            if (ntp) {
                #pragma unroll
                for (int j = 0; j < 16; ++j) {
                    const float4 ka = ldnt4f(kb + j * 128);
                    const float4 kc = ldnt4f(kb + j * 128 + 4);
                    #pragma unroll
                    for (int g = 0; g < NG; ++g) {
                        sc[g] += q[g * HD + j * 8 + 0] * ka.x + q[g * HD + j * 8 + 1] * ka.y
                               + q[g * HD + j * 8 + 2] * ka.z + q[g * HD + j * 8 + 3] * ka.w
                               + q[g * HD + j * 8 + 4] * kc.x + q[g * HD + j * 8 + 5] * kc.y
                               + q[g * HD + j * 8 + 6] * kc.z + q[g * HD + j * 8 + 7] * kc.w;
                    }
                }
            } else {
                #pragma unroll
                for (int j = 0; j < 16; ++j) {
                    const float4 ka = *(const float4*)(kb + j * 128);
                    const float4 kc = *(const float4*)(kb + j * 128 + 4);
                    #pragma unroll
                    for (int g = 0; g < NG; ++g) {
                        sc[g] += q[g * HD + j * 8 + 0] * ka.x + q[g * HD + j * 8 + 1] * ka.y
                               + q[g * HD + j * 8 + 2] * ka.z + q[g * HD + j * 8 + 3] * ka.w
                               + q[g * HD + j * 8 + 4] * kc.x + q[g * HD + j * 8 + 5] * kc.y
                               + q[g * HD + j * 8 + 6] * kc.z + q[g * HD + j * 8 + 7] * kc.w;
                    }
                }
            }

            // new-token K correction: token ctx-1's key comes from the `key` input
            if (t == ctx - 1) {
                const float4* kn4 = (const float4*)(key + ((size_t)s * KVH + kvh) * HD);
                float ns[NG] = {0.f, 0.f, 0.f, 0.f};
                #pragma unroll
                for (int c = 0; c < 32; ++c) {
                    const float4 k4 = kn4[c];
                    #pragma unroll
                    for (int g = 0; g < NG; ++g) {
                        ns[g] += q[g * HD + c * 4 + 0] * k4.x + q[g * HD + c * 4 + 1] * k4.y
                               + q[g * HD + c * 4 + 2] * k4.z + q[g * HD + c * 4 + 3] * k4.w;
                    }
                }
                #pragma unroll
                for (int g = 0; g < NG; ++g) sc[g] = ns[g];
            }

            float mv;
            if (t < ctx) {
                #pragma unroll
                for (int g = 0; g < NG; ++g) sc[g] *= SCALE_F;
                mv = fmaxf(fmaxf(sc[0], sc[1]), fmaxf(sc[2], sc[3]));
            } else {
                #pragma unroll
                for (int g = 0; g < NG; ++g) sc[g] = -1e30f;
                mv = -1e30f;
            }

            #pragma unroll
            for (int o = 32; o; o >>= 1) mv = fmaxf(mv, __shfl_xor(mv, o));
            m_w = mv;

            float pr[NG];
            #pragma unroll
            for (int g = 0; g < NG; ++g) {
                pr[g] = __expf(sc[g] - m_w);
                p_lds[wv][g][lane] = pr[g];
                l_w[g] = pr[g];
            }
            #pragma unroll
            for (int o = 32; o; o >>= 1) {
                l_w[0] += __shfl_xor(l_w[0], o);
                l_w[1] += __shfl_xor(l_w[1], o);
                l_w[2] += __shfl_xor(l_w[2], o);
                l_w[3] += __shfl_xor(l_w[3], o);
            }
        }

        if (lane == 0) {
            ml_lds[wv][0] = m_w;
            #pragma unroll
            for (int g = 0; g < NG; ++g) ml_lds[wv][1 + g] = l_w[g];
        }

        // ---- PV: contiguous 1KB V loads, nt variant for ntp items ----
        if (wact) {
            int btv[4];
            #pragma unroll
            for (int b = 0; b < 4; ++b)
                btv[b] = block_tables[s * MAXB + (tw0 >> 4) + b];  // uniform, in-bounds

            const int tl = ctx - 1 - tw0;
            const int tq = lane & 3;          // token-quad within block
            const int dl = lane >> 2;         // d sub-index 0..15

            float acc[NG][8];
            #pragma unroll
            for (int g = 0; g < NG; ++g)
                #pragma unroll
                for (int sub = 0; sub < 8; ++sub) acc[g][sub] = 0.f;

            #pragma unroll
            for (int b = 0; b < 4; ++b) {
                if (tw0 + b * 16 < ctx) {     // skip fully-masked blocks
                    const float* vb = value_cache + (size_t)btv[b] * (KVH * HD * BS)
                                                  + (size_t)kvh * (HD * BS);
                    float4 p4[NG];
                    #pragma unroll
                    for (int g = 0; g < NG; ++g)
                        p4[g] = *(const float4*)&p_lds[wv][g][b * 16 + tq * 4];
                    if (ntp) {
                        #pragma unroll
                        for (int sub = 0; sub < 8; ++sub) {
                            const float4 v4 = ldnt4f(vb + sub * 256 + lane * 4);
                            #pragma unroll
                            for (int g = 0; g < NG; ++g)
                                acc[g][sub] += p4[g].x * v4.x + p4[g].y * v4.y
                                             + p4[g].z * v4.z + p4[g].w * v4.w;
                        }
                    } else {
                        #pragma unroll
                        for (int sub = 0; sub < 8; ++sub) {
                            const float4 v4 = *(const float4*)(vb + sub * 256 + lane * 4);
                            #pragma unroll
                            for (int g = 0; g < NG; ++g)
                                acc[g][sub] += p4[g].x * v4.x + p4[g].y * v4.y
                                             + p4[g].z * v4.z + p4[g].w * v4.w;
                        }
                    }
                }
            }

            // reduce the 4 token-quad groups
            #pragma unroll
            for (int g = 0; g < NG; ++g)
                #pragma unroll
                for (int sub = 0; sub < 8; ++sub) {
                    float a = acc[g][sub];
                    a += __shfl_xor(a, 1);
                    a += __shfl_xor(a, 2);
                    acc[g][sub] = a;
                }

            // new-token V correction (post-reduce; all 4 copies stay identical)
            if (tl >= 0 && tl < WPT) {
                const int btn = block_tables[s * MAXB + ((ctx - 1) >> 4)];
                const float* vbn = value_cache + (size_t)btn * (KVH * HD * BS)
                                               + (size_t)kvh * (HD * BS) + ((ctx - 1) & 15);
                const float* vrow = value + ((size_t)s * KVH + kvh) * HD;
                #pragma unroll
                for (int sub = 0; sub < 8; ++sub) {
                    const int d = sub * 16 + dl;
                    const float dv = vrow[d] - vbn[d * BS];
                    #pragma unroll
                    for (int g = 0; g < NG; ++g)
                        acc[g][sub] += p_lds[wv][g][tl] * dv;
                }
            }

            if (tq == 0) {
                #pragma unroll
                for (int g = 0; g < NG; ++g)
                    #pragma unroll
                    for (int sub = 0; sub < 8; ++sub)
                        o_lds[wv][g * HD + sub * 16 + dl] = acc[g][sub];
            }
        } else {
            #pragma unroll
            for (int i = 0; i < 8; ++i) o_lds[wv][i * 64 + lane] = 0.f;
        }

        __syncthreads();   // merge the 4 wave records

        const float m0 = ml_lds[0][0], m1 = ml_lds[1][0], m2 = ml_lds[2][0], m3 = ml_lds[3][0];
        const float M  = fmaxf(fmaxf(m0, m1), fmaxf(m2, m3));
        const float w0 = __expf(m0 - M), w1 = __expf(m1 - M);
        const float w2 = __expf(m2 - M), w3 = __expf(m3 - M);

        float* rec = ws + (size_t)item * PSTRIDE;
        #pragma unroll
        for (int r = 0; r < 2; ++r) {
            const int idx = tid + r * 256;
            rec[idx] = w0 * o_lds[0][idx] + w1 * o_lds[1][idx]
                     + w2 * o_lds[2][idx] + w3 * o_lds[3][idx];
        }
        if (tid < NG) {
            rec[512 + tid] = w0 * ml_lds[0][1 + tid] + w1 * ml_lds[1][1 + tid]
                           + w2 * ml_lds[2][1 + tid] + w3 * ml_lds[3][1 + tid];
        }
        if (tid == 4) rec[516] = M;
        // next grab's B1 separates this item's o_lds reads from the next item's writes
    }

    // ---- end protocol: publish completion (release), once per block ----
    __syncthreads();                      // drain this block's record stores
    if (tid == 0) {
        __threadfence();                  // release: records visible device-wide
        atomicAdd(&counter[1], 1u);       // device-scope
    }

    if (blockIdx.x < NPAIRS) {
        // ---- waiter: spin until ALL workers have published ----
        if (tid == 0) {
            while (__hip_atomic_load(&counter[1], __ATOMIC_ACQUIRE,
                                     __HIP_MEMORY_SCOPE_AGENT) < NWORKERS)
                __builtin_amdgcn_s_sleep(2);
        }
        __syncthreads();
        __threadfence();                  // acquire side

        // ---- phase 2: reduce this pair's records (agent-coherent reads) ----
        const int pair = blockIdx.x;
        const int s    = pair >> 3;
        const int kvh  = pair & 7;
        const int ctx  = context_lens[s];
        const int np   = (ctx + PART - 1) / PART;
        const float* base = ws + (size_t)pair * NPART * PSTRIDE;

        float M = -1e30f;
        for (int p2 = 0; p2 < np; ++p2)
            M = fmaxf(M, cohld(base + p2 * PSTRIDE + 516));

        #pragma unroll
        for (int half = 0; half < 2; ++half) {
            const int g = (tid >> 7) + half * 2;       // 0..3
            const int d = tid & 127;
            float L = 0.f, acc = 0.f;
            for (int p2 = 0; p2 < np; ++p2) {
                const float* rec = base + p2 * PSTRIDE;
                const float w = __expf(cohld(rec + 516) - M);
                L   += w * cohld(rec + 512 + g);
                acc += w * cohld(rec + g * HD + d);
            }
            out[(size_t)s * (KVH * NG * HD) + (size_t)(kvh * NG + g) * HD + d] = acc / L;
        }
    }
}

extern "C" void kernel_launch(void* const* d_in, const int* in_sizes, int n_in,
                              void* d_out, int out_size, void* d_ws, size_t ws_size,
                              hipStream_t stream) {
    const float* query       = (const float*)d_in[0];
    const float* key         = (const float*)d_in[1];
    const float* value       = (const float*)d_in[2];
    const float* key_cache   = (const float*)d_in[3];
    const float* value_cache = (const float*)d_in[4];
    const int*   block_tables  = (const int*)d_in[5];
    const int*   context_lens  = (const int*)d_in[6];
    // d_in[7] slot_mapping unused: slot is derivable from context_lens + block_tables

    float* out = (float*)d_out;
    float* ws  = (float*)d_ws;   // records: 2048*520*4 = 4.26 MB, + 8 B counters
    unsigned int* counter = (unsigned int*)((char*)d_ws + REC_BYTES);

    (void)hipMemsetAsync(counter, 0, 2 * sizeof(unsigned int), stream);
    pa_fused_kernel<<<NWORKERS, 256, 0, stream>>>(
        query, key, value, key_cache, value_cache, block_tables, context_lens,
        ws, counter, out);
}

// Round 20
// 182.671 us; speedup vs baseline: 1.0538x; 1.0538x over previous
//
#include <hip/hip_runtime.h>

#define NSEQ   16
#define KVH    8
#define NG     4      // query heads per kv head
#define HD     128
#define BS     16
#define MAXB   256
#define PART   256    // tokens per work item (4 waves x 64)
#define NPART  16
#define NITEMS (NSEQ * KVH * NPART)   // 2048 work items
#define NPAIRS (NSEQ * KVH)           // 128
#define WPT    64     // tokens per wave
#define PSTRIDE 520   // floats per record: o[d*4+g] 512, l[4], m, pad
#define REC_BYTES ((size_t)NITEMS * PSTRIDE * 4)
#define SCALE_F 0.08838834764831845f
#define NWORKERS 1024

typedef float vf4 __attribute__((ext_vector_type(4)));
__device__ __forceinline__ float4 ldnt4f(const float* p) {
    vf4 v = __builtin_nontemporal_load((const vf4*)p);
    return make_float4(v[0], v[1], v[2], v[3]);
}

// agent-coherent scalar load (coherence-point read; cross-XCD safe)
__device__ __forceinline__ float cohld(const float* p) {
    return __hip_atomic_load(p, __ATOMIC_RELAXED, __HIP_MEMORY_SCOPE_AGENT);
}

// 4 pipelined coherence-point 8B loads: one waitcnt for 4 in-flight loads.
// sc0 sc1 = system-scope cache bypass (same path cohld uses), but batched
// and coalesced -- r19's phase-2 disaster was 28K serialized same-address
// scalar requests per block; this is ~4K coalesced, 4-deep.
__device__ __forceinline__ void ld4x2_coh(const float* a0, const float* a1,
                                          const float* a2, const float* a3,
                                          float2& r0, float2& r1,
                                          float2& r2, float2& r3) {
    asm volatile(
        "global_load_dwordx2 %0, %4, off sc0 sc1\n\t"
        "global_load_dwordx2 %1, %5, off sc0 sc1\n\t"
        "global_load_dwordx2 %2, %6, off sc0 sc1\n\t"
        "global_load_dwordx2 %3, %7, off sc0 sc1\n\t"
        "s_waitcnt vmcnt(0)"
        : "=v"(r0), "=v"(r1), "=v"(r2), "=v"(r3)
        : "v"(a0), "v"(a1), "v"(a2), "v"(a3)
        : "memory");
}

// FUSED kernel, manual end-barrier. Phase 1 = r17 verbatim (82.7us base)
// except records store o as [d][g] (reader-friendly 8B pairs). End protocol
// (r19-proven): per-block release fence + done++, blocks 0..127 spin then
// reduce their pair with deduplicated lane-parallel + batched coherent loads.
__global__ __launch_bounds__(256) void pa_fused_kernel(
    const float* __restrict__ query,
    const float* __restrict__ key,
    const float* __restrict__ value,
    const float* __restrict__ key_cache,
    const float* __restrict__ value_cache,
    const int*   __restrict__ block_tables,
    const int*   __restrict__ context_lens,
    float*       __restrict__ ws,
    unsigned int* __restrict__ counter,    // [0]=steal, [1]=done
    float*       __restrict__ out)
{
    __shared__ float p_lds[4][NG][WPT];
    __shared__ float o_lds[4][NG * HD];
    __shared__ float ml_lds[4][8];
    __shared__ int   item_s;

    const int tid  = threadIdx.x;
    const int wv   = tid >> 6;
    const int lane = tid & 63;

    for (;;) {
        if (tid == 0) item_s = (int)atomicAdd(&counter[0], 1u);
        __syncthreads();                  // B1: item_s write visible
        const int item = item_s;
        __syncthreads();                  // B2: all have read; safe to overwrite later
        if (item >= NITEMS) break;        // drained -> end protocol

        const int p   = item & (NPART - 1);
        const int kvh = (item >> 4) & (KVH - 1);
        const int s   = item >> 7;
        const int ctx = context_lens[s];
        const int t0  = p * PART;
        if (t0 >= ctx) continue;          // barrier-safe skip

        const bool ntp = ((p & 3) == 3);  // 25% nt cache partitioning (r17)

        const int tw0  = t0 + wv * WPT;
        const bool wact = (tw0 < ctx);

        const float* q = query + ((size_t)s * KVH + kvh) * (NG * HD);

        float m_w = -1e30f;
        float l_w[NG] = {0.f, 0.f, 0.f, 0.f};

        if (wact) {
            // ---- QK: one token per lane ----
            const int t  = tw0 + lane;                     // < 4096: in-bounds
            const int bt = block_tables[s * MAXB + (t >> 4)];
            const float* kb = key_cache + (size_t)bt * (KVH * HD * BS)
                                        + (size_t)kvh * (HD * BS) + (t & 15) * 8;

            float sc[NG] = {0.f, 0.f, 0.f, 0.f};
            if (ntp) {
                #pragma unroll
                for (int j = 0; j < 16; ++j) {
                    const float4 ka = ldnt4f(kb + j * 128);
                    const float4 kc = ldnt4f(kb + j * 128 + 4);
                    #pragma unroll
                    for (int g = 0; g < NG; ++g) {
                        sc[g] += q[g * HD + j * 8 + 0] * ka.x + q[g * HD + j * 8 + 1] * ka.y
                               + q[g * HD + j * 8 + 2] * ka.z + q[g * HD + j * 8 + 3] * ka.w
                               + q[g * HD + j * 8 + 4] * kc.x + q[g * HD + j * 8 + 5] * kc.y
                               + q[g * HD + j * 8 + 6] * kc.z + q[g * HD + j * 8 + 7] * kc.w;
                    }
                }
            } else {
                #pragma unroll
                for (int j = 0; j < 16; ++j) {
                    const float4 ka = *(const float4*)(kb + j * 128);
                    const float4 kc = *(const float4*)(kb + j * 128 + 4);
                    #pragma unroll
                    for (int g = 0; g < NG; ++g) {
                        sc[g] += q[g * HD + j * 8 + 0] * ka.x + q[g * HD + j * 8 + 1] * ka.y
                               + q[g * HD + j * 8 + 2] * ka.z + q[g * HD + j * 8 + 3] * ka.w
                               + q[g * HD + j * 8 + 4] * kc.x + q[g * HD + j * 8 + 5] * kc.y
                               + q[g * HD + j * 8 + 6] * kc.z + q[g * HD + j * 8 + 7] * kc.w;
                    }
                }
            }

            // new-token K correction
            if (t == ctx - 1) {
                const float4* kn4 = (const float4*)(key + ((size_t)s * KVH + kvh) * HD);
                float ns[NG] = {0.f, 0.f, 0.f, 0.f};
                #pragma unroll
                for (int c = 0; c < 32; ++c) {
                    const float4 k4 = kn4[c];
                    #pragma unroll
                    for (int g = 0; g < NG; ++g) {
                        ns[g] += q[g * HD + c * 4 + 0] * k4.x + q[g * HD + c * 4 + 1] * k4.y
                               + q[g * HD + c * 4 + 2] * k4.z + q[g * HD + c * 4 + 3] * k4.w;
                    }
                }
                #pragma unroll
                for (int g = 0; g < NG; ++g) sc[g] = ns[g];
            }

            float mv;
            if (t < ctx) {
                #pragma unroll
                for (int g = 0; g < NG; ++g) sc[g] *= SCALE_F;
                mv = fmaxf(fmaxf(sc[0], sc[1]), fmaxf(sc[2], sc[3]));
            } else {
                #pragma unroll
                for (int g = 0; g < NG; ++g) sc[g] = -1e30f;
                mv = -1e30f;
            }

            #pragma unroll
            for (int o = 32; o; o >>= 1) mv = fmaxf(mv, __shfl_xor(mv, o));
            m_w = mv;

            float pr[NG];
            #pragma unroll
            for (int g = 0; g < NG; ++g) {
                pr[g] = __expf(sc[g] - m_w);
                p_lds[wv][g][lane] = pr[g];
                l_w[g] = pr[g];
            }
            #pragma unroll
            for (int o = 32; o; o >>= 1) {
                l_w[0] += __shfl_xor(l_w[0], o);
                l_w[1] += __shfl_xor(l_w[1], o);
                l_w[2] += __shfl_xor(l_w[2], o);
                l_w[3] += __shfl_xor(l_w[3], o);
            }
        }

        if (lane == 0) {
            ml_lds[wv][0] = m_w;
            #pragma unroll
            for (int g = 0; g < NG; ++g) ml_lds[wv][1 + g] = l_w[g];
        }

        // ---- PV: contiguous 1KB V loads (r15/r17) ----
        if (wact) {
            int btv[4];
            #pragma unroll
            for (int b = 0; b < 4; ++b)
                btv[b] = block_tables[s * MAXB + (tw0 >> 4) + b];

            const int tl = ctx - 1 - tw0;
            const int tq = lane & 3;
            const int dl = lane >> 2;

            float acc[NG][8];
            #pragma unroll
            for (int g = 0; g < NG; ++g)
                #pragma unroll
                for (int sub = 0; sub < 8; ++sub) acc[g][sub] = 0.f;

            #pragma unroll
            for (int b = 0; b < 4; ++b) {
                if (tw0 + b * 16 < ctx) {
                    const float* vb = value_cache + (size_t)btv[b] * (KVH * HD * BS)
                                                  + (size_t)kvh * (HD * BS);
                    float4 p4[NG];
                    #pragma unroll
                    for (int g = 0; g < NG; ++g)
                        p4[g] = *(const float4*)&p_lds[wv][g][b * 16 + tq * 4];
                    if (ntp) {
                        #pragma unroll
                        for (int sub = 0; sub < 8; ++sub) {
                            const float4 v4 = ldnt4f(vb + sub * 256 + lane * 4);
                            #pragma unroll
                            for (int g = 0; g < NG; ++g)
                                acc[g][sub] += p4[g].x * v4.x + p4[g].y * v4.y
                                             + p4[g].z * v4.z + p4[g].w * v4.w;
                        }
                    } else {
                        #pragma unroll
                        for (int sub = 0; sub < 8; ++sub) {
                            const float4 v4 = *(const float4*)(vb + sub * 256 + lane * 4);
                            #pragma unroll
                            for (int g = 0; g < NG; ++g)
                                acc[g][sub] += p4[g].x * v4.x + p4[g].y * v4.y
                                             + p4[g].z * v4.z + p4[g].w * v4.w;
                        }
                    }
                }
            }

            #pragma unroll
            for (int g = 0; g < NG; ++g)
                #pragma unroll
                for (int sub = 0; sub < 8; ++sub) {
                    float a = acc[g][sub];
                    a += __shfl_xor(a, 1);
                    a += __shfl_xor(a, 2);
                    acc[g][sub] = a;
                }

            if (tl >= 0 && tl < WPT) {
                const int btn = block_tables[s * MAXB + ((ctx - 1) >> 4)];
                const float* vbn = value_cache + (size_t)btn * (KVH * HD * BS)
                                               + (size_t)kvh * (HD * BS) + ((ctx - 1) & 15);
                const float* vrow = value + ((size_t)s * KVH + kvh) * HD;
                #pragma unroll
                for (int sub = 0; sub < 8; ++sub) {
                    const int d = sub * 16 + dl;
                    const float dv = vrow[d] - vbn[d * BS];
                    #pragma unroll
                    for (int g = 0; g < NG; ++g)
                        acc[g][sub] += p_lds[wv][g][tl] * dv;
                }
            }

            if (tq == 0) {
                #pragma unroll
                for (int g = 0; g < NG; ++g)
                    #pragma unroll
                    for (int sub = 0; sub < 8; ++sub)
                        o_lds[wv][g * HD + sub * 16 + dl] = acc[g][sub];
            }
        } else {
            #pragma unroll
            for (int i = 0; i < 8; ++i) o_lds[wv][i * 64 + lane] = 0.f;
        }

        __syncthreads();   // merge the 4 wave records

        const float m0 = ml_lds[0][0], m1 = ml_lds[1][0], m2 = ml_lds[2][0], m3 = ml_lds[3][0];
        const float M  = fmaxf(fmaxf(m0, m1), fmaxf(m2, m3));
        const float w0 = __expf(m0 - M), w1 = __expf(m1 - M);
        const float w2 = __expf(m2 - M), w3 = __expf(m3 - M);

        float* rec = ws + (size_t)item * PSTRIDE;
        #pragma unroll
        for (int r = 0; r < 2; ++r) {
            const int idx = tid + r * 256;            // idx = g*128 + d
            // store o as [d][g] so phase-2 reads are aligned 8B pairs
            rec[(idx & 127) * 4 + (idx >> 7)] =
                  w0 * o_lds[0][idx] + w1 * o_lds[1][idx]
                + w2 * o_lds[2][idx] + w3 * o_lds[3][idx];
        }
        if (tid < NG) {
            rec[512 + tid] = w0 * ml_lds[0][1 + tid] + w1 * ml_lds[1][1 + tid]
                           + w2 * ml_lds[2][1 + tid] + w3 * ml_lds[3][1 + tid];
        }
        if (tid == 4) rec[516] = M;
    }

    // ---- end protocol: publish completion (release), once per block ----
    __syncthreads();                      // drain this block's record stores
    if (tid == 0) {
        __threadfence();                  // release: records visible device-wide
        atomicAdd(&counter[1], 1u);
    }

    if (blockIdx.x < NPAIRS) {
        if (tid == 0) {
            while (__hip_atomic_load(&counter[1], __ATOMIC_ACQUIRE,
                                     __HIP_MEMORY_SCOPE_AGENT) < NWORKERS)
                __builtin_amdgcn_s_sleep(2);
        }
        __syncthreads();
        __threadfence();                  // acquire side

        // ---- phase 2: dedup'd lane-parallel + batched coherent reads ----
        const int pair = blockIdx.x;
        const int s    = pair >> 3;
        const int kvh  = pair & 7;
        const int ctx  = context_lens[s];
        const int np   = (ctx + PART - 1) / PART;
        const float* base = ws + (size_t)pair * NPART * PSTRIDE;

        // lane-parallel m: lane's partition pl = lane&15 (1 instr/wave)
        const int pl = lane & 15;
        const float mraw = cohld(base + pl * PSTRIDE + 516);
        const float mval = (pl < np) ? mraw : -1e30f;   // SELECT, not x0 (NaN-safe)
        float M2 = mval;
        #pragma unroll
        for (int o = 8; o; o >>= 1) M2 = fmaxf(M2, __shfl_xor(M2, o));
        const float w_l = (pl < np) ? __expf(mval - M2) : 0.f;  // lane i<16: w of part i

        // lane-parallel l: lane covers (partition lane>>2, head lane&3)
        const int pl2 = lane >> 2, g2 = lane & 3;
        const float lraw = cohld(base + pl2 * PSTRIDE + 512 + g2);
        const float wp2  = __shfl(w_l, pl2);
        float lsum = (pl2 < np) ? wp2 * lraw : 0.f;
        #pragma unroll
        for (int o = 4; o <= 32; o <<= 1) lsum += __shfl_xor(lsum, o);
        // lane g (g<4) now holds L_g

        // acc: thread = (d, gh) reads 16x 8B [d][2gh..2gh+1] pairs, 4-deep
        const int d  = tid & 127;
        const int gh = tid >> 7;
        const float* ab = base + d * 4 + gh * 2;
        float2 v[16];
        ld4x2_coh(ab + 0 * PSTRIDE, ab + 1 * PSTRIDE, ab + 2 * PSTRIDE, ab + 3 * PSTRIDE,
                  v[0], v[1], v[2], v[3]);
        ld4x2_coh(ab + 4 * PSTRIDE, ab + 5 * PSTRIDE, ab + 6 * PSTRIDE, ab + 7 * PSTRIDE,
                  v[4], v[5], v[6], v[7]);
        ld4x2_coh(ab + 8 * PSTRIDE, ab + 9 * PSTRIDE, ab + 10 * PSTRIDE, ab + 11 * PSTRIDE,
                  v[8], v[9], v[10], v[11]);
        ld4x2_coh(ab + 12 * PSTRIDE, ab + 13 * PSTRIDE, ab + 14 * PSTRIDE, ab + 15 * PSTRIDE,
                  v[12], v[13], v[14], v[15]);

        float a0 = 0.f, a1 = 0.f;
        #pragma unroll
        for (int p2 = 0; p2 < 16; ++p2) {
            const float wp = __shfl(w_l, p2);
            const float x = (p2 < np) ? v[p2].x : 0.f;   // SELECT garbage off
            const float y = (p2 < np) ? v[p2].y : 0.f;
            a0 += wp * x;
            a1 += wp * y;
        }

        const float L0 = __shfl(lsum, gh * 2);
        const float L1 = __shfl(lsum, gh * 2 + 1);
        float* ob = out + (size_t)s * (KVH * NG * HD) + (size_t)(kvh * NG) * HD;
        ob[(gh * 2 + 0) * HD + d] = a0 / L0;
        ob[(gh * 2 + 1) * HD + d] = a1 / L1;
    }
}

extern "C" void kernel_launch(void* const* d_in, const int* in_sizes, int n_in,
                              void* d_out, int out_size, void* d_ws, size_t ws_size,
                              hipStream_t stream) {
    const float* query       = (const float*)d_in[0];
    const float* key         = (const float*)d_in[1];
    const float* value       = (const float*)d_in[2];
    const float* key_cache   = (const float*)d_in[3];
    const float* value_cache = (const float*)d_in[4];
    const int*   block_tables  = (const int*)d_in[5];
    const int*   context_lens  = (const int*)d_in[6];
    // d_in[7] slot_mapping unused: slot is derivable from context_lens + block_tables

    float* out = (float*)d_out;
    float* ws  = (float*)d_ws;   // records: 2048*520*4 = 4.26 MB, + 8 B counters
    unsigned int* counter = (unsigned int*)((char*)d_ws + REC_BYTES);

    (void)hipMemsetAsync(counter, 0, 2 * sizeof(unsigned int), stream);
    pa_fused_kernel<<<NWORKERS, 256, 0, stream>>>(
        query, key, value, key_cache, value_cache, block_tables, context_lens,
        ws, counter, out);
}

// Round 21
// 132.546 us; speedup vs baseline: 1.4523x; 1.3782x over previous
//
#include <hip/hip_runtime.h>

#define NSEQ   16
#define KVH    8
#define NG     4      // query heads per kv head
#define HD     128
#define BS     16
#define MAXB   256
#define PART   256    // tokens per work item (4 waves x 64)
#define NPART  16
#define NITEMS (NSEQ * KVH * NPART)   // 2048 work items
#define NPAIRS (NSEQ * KVH)           // 128
#define WPT    64     // tokens per wave
#define PSTRIDE 520   // floats per record: o[d*4+g] 512, l[4], m, pad
#define REC_BYTES ((size_t)NITEMS * PSTRIDE * 4)
#define SCALE_F 0.08838834764831845f
#define NWORKERS 1024

typedef float vf4 __attribute__((ext_vector_type(4)));
__device__ __forceinline__ float4 ldnt4f(const float* p) {
    vf4 v = __builtin_nontemporal_load((const vf4*)p);
    return make_float4(v[0], v[1], v[2], v[3]);
}

// agent-coherent scalar load (coherence-point read; cross-XCD safe; r20-proven)
__device__ __forceinline__ float cohld(const float* p) {
    return __hip_atomic_load(p, __ATOMIC_RELAXED, __HIP_MEMORY_SCOPE_AGENT);
}

// system-scope stores: visible at the coherence point once vmcnt retires.
// NO __threadfence needed anywhere -> no L2 writeback scans (the r16/r19/r20
// fused versions lost ~150us to 1024+ device-scope fences; replays showed
// 230us at ~zero HBM traffic -- the time was fence serialization, not loads).
__device__ __forceinline__ void st2_coh(float* p, float a, float b) {
    float2 v = make_float2(a, b);
    asm volatile("global_store_dwordx2 %0, %1, off sc0 sc1"
                 :: "v"(p), "v"(v) : "memory");
}
__device__ __forceinline__ void st1_coh(float* p, float a) {
    asm volatile("global_store_dword %0, %1, off sc0 sc1"
                 :: "v"(p), "v"(a) : "memory");
}

// 4 pipelined coherence-point 8B loads (r20-proven phase-2 read path)
__device__ __forceinline__ void ld4x2_coh(const float* a0, const float* a1,
                                          const float* a2, const float* a3,
                                          float2& r0, float2& r1,
                                          float2& r2, float2& r3) {
    asm volatile(
        "global_load_dwordx2 %0, %4, off sc0 sc1\n\t"
        "global_load_dwordx2 %1, %5, off sc0 sc1\n\t"
        "global_load_dwordx2 %2, %6, off sc0 sc1\n\t"
        "global_load_dwordx2 %3, %7, off sc0 sc1\n\t"
        "s_waitcnt vmcnt(0)"
        : "=v"(r0), "=v"(r1), "=v"(r2), "=v"(r3)
        : "v"(a0), "v"(a1), "v"(a2), "v"(a3)
        : "memory");
}

// FUSED kernel, FENCE-FREE end protocol.
// Phase 1: r17's body (steal loop, 4 independent waves, wave-local softmax,
//   contiguous-V PV, 25% nt). Records stored via sc0/sc1 system-scope stores.
// End: __syncthreads (drains vmcnt -> stores at coherence point) + relaxed
//   done++ per block. Blocks 0..127 spin on relaxed agent loads, then reduce
//   their pair with batched coherent loads. Workers never wait -> no deadlock.
__global__ __launch_bounds__(256) void pa_fused_kernel(
    const float* __restrict__ query,
    const float* __restrict__ key,
    const float* __restrict__ value,
    const float* __restrict__ key_cache,
    const float* __restrict__ value_cache,
    const int*   __restrict__ block_tables,
    const int*   __restrict__ context_lens,
    float*       __restrict__ ws,
    unsigned int* __restrict__ counter,    // [0]=steal, [1]=done
    float*       __restrict__ out)
{
    __shared__ float p_lds[4][NG][WPT];
    __shared__ float o_lds[4][NG * HD];
    __shared__ float ml_lds[4][8];
    __shared__ int   item_s;

    const int tid  = threadIdx.x;
    const int wv   = tid >> 6;
    const int lane = tid & 63;

    for (;;) {
        if (tid == 0) item_s = (int)atomicAdd(&counter[0], 1u);
        __syncthreads();                  // B1: item_s write visible
        const int item = item_s;
        __syncthreads();                  // B2: all have read; safe to overwrite later
        if (item >= NITEMS) break;        // drained -> end protocol

        const int p   = item & (NPART - 1);
        const int kvh = (item >> 4) & (KVH - 1);
        const int s   = item >> 7;
        const int ctx = context_lens[s];
        const int t0  = p * PART;
        if (t0 >= ctx) continue;          // barrier-safe skip

        const bool ntp = ((p & 3) == 3);  // 25% nt cache partitioning (r17)

        const int tw0  = t0 + wv * WPT;
        const bool wact = (tw0 < ctx);

        const float* q = query + ((size_t)s * KVH + kvh) * (NG * HD);

        float m_w = -1e30f;
        float l_w[NG] = {0.f, 0.f, 0.f, 0.f};

        if (wact) {
            // ---- QK: one token per lane ----
            const int t  = tw0 + lane;                     // < 4096: in-bounds
            const int bt = block_tables[s * MAXB + (t >> 4)];
            const float* kb = key_cache + (size_t)bt * (KVH * HD * BS)
                                        + (size_t)kvh * (HD * BS) + (t & 15) * 8;

            float sc[NG] = {0.f, 0.f, 0.f, 0.f};
            if (ntp) {
                #pragma unroll
                for (int j = 0; j < 16; ++j) {
                    const float4 ka = ldnt4f(kb + j * 128);
                    const float4 kc = ldnt4f(kb + j * 128 + 4);
                    #pragma unroll
                    for (int g = 0; g < NG; ++g) {
                        sc[g] += q[g * HD + j * 8 + 0] * ka.x + q[g * HD + j * 8 + 1] * ka.y
                               + q[g * HD + j * 8 + 2] * ka.z + q[g * HD + j * 8 + 3] * ka.w
                               + q[g * HD + j * 8 + 4] * kc.x + q[g * HD + j * 8 + 5] * kc.y
                               + q[g * HD + j * 8 + 6] * kc.z + q[g * HD + j * 8 + 7] * kc.w;
                    }
                }
            } else {
                #pragma unroll
                for (int j = 0; j < 16; ++j) {
                    const float4 ka = *(const float4*)(kb + j * 128);
                    const float4 kc = *(const float4*)(kb + j * 128 + 4);
                    #pragma unroll
                    for (int g = 0; g < NG; ++g) {
                        sc[g] += q[g * HD + j * 8 + 0] * ka.x + q[g * HD + j * 8 + 1] * ka.y
                               + q[g * HD + j * 8 + 2] * ka.z + q[g * HD + j * 8 + 3] * ka.w
                               + q[g * HD + j * 8 + 4] * kc.x + q[g * HD + j * 8 + 5] * kc.y
                               + q[g * HD + j * 8 + 6] * kc.z + q[g * HD + j * 8 + 7] * kc.w;
                    }
                }
            }

            // new-token K correction
            if (t == ctx - 1) {
                const float4* kn4 = (const float4*)(key + ((size_t)s * KVH + kvh) * HD);
                float ns[NG] = {0.f, 0.f, 0.f, 0.f};
                #pragma unroll
                for (int c = 0; c < 32; ++c) {
                    const float4 k4 = kn4[c];
                    #pragma unroll
                    for (int g = 0; g < NG; ++g) {
                        ns[g] += q[g * HD + c * 4 + 0] * k4.x + q[g * HD + c * 4 + 1] * k4.y
                               + q[g * HD + c * 4 + 2] * k4.z + q[g * HD + c * 4 + 3] * k4.w;
                    }
                }
                #pragma unroll
                for (int g = 0; g < NG; ++g) sc[g] = ns[g];
            }

            float mv;
            if (t < ctx) {
                #pragma unroll
                for (int g = 0; g < NG; ++g) sc[g] *= SCALE_F;
                mv = fmaxf(fmaxf(sc[0], sc[1]), fmaxf(sc[2], sc[3]));
            } else {
                #pragma unroll
                for (int g = 0; g < NG; ++g) sc[g] = -1e30f;
                mv = -1e30f;
            }

            #pragma unroll
            for (int o = 32; o; o >>= 1) mv = fmaxf(mv, __shfl_xor(mv, o));
            m_w = mv;

            float pr[NG];
            #pragma unroll
            for (int g = 0; g < NG; ++g) {
                pr[g] = __expf(sc[g] - m_w);
                p_lds[wv][g][lane] = pr[g];
                l_w[g] = pr[g];
            }
            #pragma unroll
            for (int o = 32; o; o >>= 1) {
                l_w[0] += __shfl_xor(l_w[0], o);
                l_w[1] += __shfl_xor(l_w[1], o);
                l_w[2] += __shfl_xor(l_w[2], o);
                l_w[3] += __shfl_xor(l_w[3], o);
            }
        }

        if (lane == 0) {
            ml_lds[wv][0] = m_w;
            #pragma unroll
            for (int g = 0; g < NG; ++g) ml_lds[wv][1 + g] = l_w[g];
        }

        // ---- PV: contiguous 1KB V loads (r15/r17) ----
        if (wact) {
            int btv[4];
            #pragma unroll
            for (int b = 0; b < 4; ++b)
                btv[b] = block_tables[s * MAXB + (tw0 >> 4) + b];

            const int tl = ctx - 1 - tw0;
            const int tq = lane & 3;
            const int dl = lane >> 2;

            float acc[NG][8];
            #pragma unroll
            for (int g = 0; g < NG; ++g)
                #pragma unroll
                for (int sub = 0; sub < 8; ++sub) acc[g][sub] = 0.f;

            #pragma unroll
            for (int b = 0; b < 4; ++b) {
                if (tw0 + b * 16 < ctx) {
                    const float* vb = value_cache + (size_t)btv[b] * (KVH * HD * BS)
                                                  + (size_t)kvh * (HD * BS);
                    float4 p4[NG];
                    #pragma unroll
                    for (int g = 0; g < NG; ++g)
                        p4[g] = *(const float4*)&p_lds[wv][g][b * 16 + tq * 4];
                    if (ntp) {
                        #pragma unroll
                        for (int sub = 0; sub < 8; ++sub) {
                            const float4 v4 = ldnt4f(vb + sub * 256 + lane * 4);
                            #pragma unroll
                            for (int g = 0; g < NG; ++g)
                                acc[g][sub] += p4[g].x * v4.x + p4[g].y * v4.y
                                             + p4[g].z * v4.z + p4[g].w * v4.w;
                        }
                    } else {
                        #pragma unroll
                        for (int sub = 0; sub < 8; ++sub) {
                            const float4 v4 = *(const float4*)(vb + sub * 256 + lane * 4);
                            #pragma unroll
                            for (int g = 0; g < NG; ++g)
                                acc[g][sub] += p4[g].x * v4.x + p4[g].y * v4.y
                                             + p4[g].z * v4.z + p4[g].w * v4.w;
                        }
                    }
                }
            }

            #pragma unroll
            for (int g = 0; g < NG; ++g)
                #pragma unroll
                for (int sub = 0; sub < 8; ++sub) {
                    float a = acc[g][sub];
                    a += __shfl_xor(a, 1);
                    a += __shfl_xor(a, 2);
                    acc[g][sub] = a;
                }

            if (tl >= 0 && tl < WPT) {
                const int btn = block_tables[s * MAXB + ((ctx - 1) >> 4)];
                const float* vbn = value_cache + (size_t)btn * (KVH * HD * BS)
                                               + (size_t)kvh * (HD * BS) + ((ctx - 1) & 15);
                const float* vrow = value + ((size_t)s * KVH + kvh) * HD;
                #pragma unroll
                for (int sub = 0; sub < 8; ++sub) {
                    const int d = sub * 16 + dl;
                    const float dv = vrow[d] - vbn[d * BS];
                    #pragma unroll
                    for (int g = 0; g < NG; ++g)
                        acc[g][sub] += p_lds[wv][g][tl] * dv;
                }
            }

            if (tq == 0) {
                #pragma unroll
                for (int g = 0; g < NG; ++g)
                    #pragma unroll
                    for (int sub = 0; sub < 8; ++sub)
                        o_lds[wv][g * HD + sub * 16 + dl] = acc[g][sub];
            }
        } else {
            #pragma unroll
            for (int i = 0; i < 8; ++i) o_lds[wv][i * 64 + lane] = 0.f;
        }

        __syncthreads();   // merge the 4 wave records

        const float m0 = ml_lds[0][0], m1 = ml_lds[1][0], m2 = ml_lds[2][0], m3 = ml_lds[3][0];
        const float M  = fmaxf(fmaxf(m0, m1), fmaxf(m2, m3));
        const float w0 = __expf(m0 - M), w1 = __expf(m1 - M);
        const float w2 = __expf(m2 - M), w3 = __expf(m3 - M);

        // record write: [d][g] layout, one coherent float2 store per thread
        float* rec = ws + (size_t)item * PSTRIDE;
        {
            const int d  = tid & 127;
            const int gp = tid >> 7;              // 0: g=0,1   1: g=2,3
            const int g0 = gp * 2, g1 = gp * 2 + 1;
            const float v0 = w0 * o_lds[0][g0 * HD + d] + w1 * o_lds[1][g0 * HD + d]
                           + w2 * o_lds[2][g0 * HD + d] + w3 * o_lds[3][g0 * HD + d];
            const float v1 = w0 * o_lds[0][g1 * HD + d] + w1 * o_lds[1][g1 * HD + d]
                           + w2 * o_lds[2][g1 * HD + d] + w3 * o_lds[3][g1 * HD + d];
            st2_coh(rec + d * 4 + gp * 2, v0, v1);
        }
        if (tid < NG) {
            st1_coh(rec + 512 + tid,
                    w0 * ml_lds[0][1 + tid] + w1 * ml_lds[1][1 + tid]
                  + w2 * ml_lds[2][1 + tid] + w3 * ml_lds[3][1 + tid]);
        }
        if (tid == 4) st1_coh(rec + 516, M);
    }

    // ---- end protocol: NO FENCE. __syncthreads drains vmcnt (sc0/sc1 stores
    // are at the coherence point once acked); then a relaxed done++ ----
    __syncthreads();
    if (tid == 0)
        __hip_atomic_fetch_add(&counter[1], 1u, __ATOMIC_RELAXED,
                               __HIP_MEMORY_SCOPE_AGENT);

    if (blockIdx.x < NPAIRS) {
        if (tid == 0) {
            while (__hip_atomic_load(&counter[1], __ATOMIC_RELAXED,
                                     __HIP_MEMORY_SCOPE_AGENT) < NWORKERS)
                __builtin_amdgcn_s_sleep(2);
        }
        __syncthreads();

        // ---- phase 2 (r20-proven): dedup'd lane-parallel + batched reads ----
        const int pair = blockIdx.x;
        const int s    = pair >> 3;
        const int kvh  = pair & 7;
        const int ctx  = context_lens[s];
        const int np   = (ctx + PART - 1) / PART;
        const float* base = ws + (size_t)pair * NPART * PSTRIDE;

        const int pl = lane & 15;
        const float mraw = cohld(base + pl * PSTRIDE + 516);
        const float mval = (pl < np) ? mraw : -1e30f;   // SELECT (NaN-safe)
        float M2 = mval;
        #pragma unroll
        for (int o = 8; o; o >>= 1) M2 = fmaxf(M2, __shfl_xor(M2, o));
        const float w_l = (pl < np) ? __expf(mval - M2) : 0.f;

        const int pl2 = lane >> 2, g2 = lane & 3;
        const float lraw = cohld(base + pl2 * PSTRIDE + 512 + g2);
        const float wp2  = __shfl(w_l, pl2);
        float lsum = (pl2 < np) ? wp2 * lraw : 0.f;
        #pragma unroll
        for (int o = 4; o <= 32; o <<= 1) lsum += __shfl_xor(lsum, o);

        const int d  = tid & 127;
        const int gh = tid >> 7;
        const float* ab = base + d * 4 + gh * 2;
        float2 v[16];
        ld4x2_coh(ab + 0 * PSTRIDE, ab + 1 * PSTRIDE, ab + 2 * PSTRIDE, ab + 3 * PSTRIDE,
                  v[0], v[1], v[2], v[3]);
        ld4x2_coh(ab + 4 * PSTRIDE, ab + 5 * PSTRIDE, ab + 6 * PSTRIDE, ab + 7 * PSTRIDE,
                  v[4], v[5], v[6], v[7]);
        ld4x2_coh(ab + 8 * PSTRIDE, ab + 9 * PSTRIDE, ab + 10 * PSTRIDE, ab + 11 * PSTRIDE,
                  v[8], v[9], v[10], v[11]);
        ld4x2_coh(ab + 12 * PSTRIDE, ab + 13 * PSTRIDE, ab + 14 * PSTRIDE, ab + 15 * PSTRIDE,
                  v[12], v[13], v[14], v[15]);

        float a0 = 0.f, a1 = 0.f;
        #pragma unroll
        for (int p2 = 0; p2 < 16; ++p2) {
            const float wp = __shfl(w_l, p2);
            const float x = (p2 < np) ? v[p2].x : 0.f;
            const float y = (p2 < np) ? v[p2].y : 0.f;
            a0 += wp * x;
            a1 += wp * y;
        }

        const float L0 = __shfl(lsum, gh * 2);
        const float L1 = __shfl(lsum, gh * 2 + 1);
        float* ob = out + (size_t)s * (KVH * NG * HD) + (size_t)(kvh * NG) * HD;
        ob[(gh * 2 + 0) * HD + d] = a0 / L0;
        ob[(gh * 2 + 1) * HD + d] = a1 / L1;
    }
}

extern "C" void kernel_launch(void* const* d_in, const int* in_sizes, int n_in,
                              void* d_out, int out_size, void* d_ws, size_t ws_size,
                              hipStream_t stream) {
    const float* query       = (const float*)d_in[0];
    const float* key         = (const float*)d_in[1];
    const float* value       = (const float*)d_in[2];
    const float* key_cache   = (const float*)d_in[3];
    const float* value_cache = (const float*)d_in[4];
    const int*   block_tables  = (const int*)d_in[5];
    const int*   context_lens  = (const int*)d_in[6];
    // d_in[7] slot_mapping unused: slot is derivable from context_lens + block_tables

    float* out = (float*)d_out;
    float* ws  = (float*)d_ws;   // records: 2048*520*4 = 4.26 MB, + 8 B counters
    unsigned int* counter = (unsigned int*)((char*)d_ws + REC_BYTES);

    (void)hipMemsetAsync(counter, 0, 2 * sizeof(unsigned int), stream);
    pa_fused_kernel<<<NWORKERS, 256, 0, stream>>>(
        query, key, value, key_cache, value_cache, block_tables, context_lens,
        ws, counter, out);
}

// Round 22
// 82.279 us; speedup vs baseline: 2.3396x; 1.6109x over previous
//
#include <hip/hip_runtime.h>

#define NSEQ   16
#define KVH    8
#define NG     4      // query heads per kv head
#define HD     128
#define BS     16
#define MAXB   256
#define PART   256    // tokens per work item (4 waves x 64)
#define NPART  16
#define NITEMS (NSEQ * KVH * NPART)   // 2048 work items
#define WPT    64     // tokens per wave
#define PSTRIDE 520   // floats per partition record: o[512], l[4], m, pad
#define REC_BYTES ((size_t)NITEMS * PSTRIDE * 4)
#define SCALE_F 0.08838834764831845f
#define NWORKERS 1024

typedef float vf4 __attribute__((ext_vector_type(4)));
__device__ __forceinline__ float4 ldnt4f(const float* p) {
    vf4 v = __builtin_nontemporal_load((const vf4*)p);
    return make_float4(v[0], v[1], v[2], v[3]);
}

// r17 EXACT REVERT — session optimum (82.7us). Two kernels; fusion attempts
// r16/r18/r19/r20/r21 all lost 50-150us to cross-XCD coherence costs (device
// fences = L2 writeback scans; coherent scalar reads; uncached record stores),
// far exceeding the ~11us two-dispatch overhead they tried to save.
// Kernel 1: block work stealing (two-barrier grab), 4 independent waves x 64
// tokens, wave-local softmax, contiguous-V PV, 25% nt cache partitioning.
__global__ __launch_bounds__(256) void pa_partial_kernel(
    const float* __restrict__ query,
    const float* __restrict__ key,
    const float* __restrict__ value,
    const float* __restrict__ key_cache,
    const float* __restrict__ value_cache,
    const int*   __restrict__ block_tables,
    const int*   __restrict__ context_lens,
    float*       __restrict__ ws,
    unsigned int* __restrict__ counter)
{
    __shared__ float p_lds[4][NG][WPT];   // per-wave probabilities
    __shared__ float o_lds[4][NG * HD];   // per-wave partial outputs
    __shared__ float ml_lds[4][8];        // per-wave m, l[4]
    __shared__ int   item_s;

    const int tid  = threadIdx.x;
    const int wv   = tid >> 6;
    const int lane = tid & 63;

    for (;;) {
        if (tid == 0) item_s = (int)atomicAdd(counter, 1u);
        __syncthreads();                  // B1: item_s write visible
        const int item = item_s;
        __syncthreads();                  // B2: all have read; safe to overwrite later
        if (item >= NITEMS) return;

        const int p   = item & (NPART - 1);
        const int kvh = (item >> 4) & (KVH - 1);
        const int s   = item >> 7;
        const int ctx = context_lens[s];
        const int t0  = p * PART;
        if (t0 >= ctx) continue;          // barrier-safe skip

        const bool ntp = ((p & 3) == 3);  // wave-uniform nt decision (25% of items)

        const int tw0  = t0 + wv * WPT;
        const bool wact = (tw0 < ctx);

        const float* q = query + ((size_t)s * KVH + kvh) * (NG * HD);

        float m_w = -1e30f;
        float l_w[NG] = {0.f, 0.f, 0.f, 0.f};

        if (wact) {
            // ---- QK: one token per lane ----
            const int t  = tw0 + lane;                     // < 4096: in-bounds
            const int bt = block_tables[s * MAXB + (t >> 4)];
            const float* kb = key_cache + (size_t)bt * (KVH * HD * BS)
                                        + (size_t)kvh * (HD * BS) + (t & 15) * 8;

            float sc[NG] = {0.f, 0.f, 0.f, 0.f};
            if (ntp) {
                #pragma unroll
                for (int j = 0; j < 16; ++j) {
                    const float4 ka = ldnt4f(kb + j * 128);
                    const float4 kc = ldnt4f(kb + j * 128 + 4);
                    #pragma unroll
                    for (int g = 0; g < NG; ++g) {
                        sc[g] += q[g * HD + j * 8 + 0] * ka.x + q[g * HD + j * 8 + 1] * ka.y
                               + q[g * HD + j * 8 + 2] * ka.z + q[g * HD + j * 8 + 3] * ka.w
                               + q[g * HD + j * 8 + 4] * kc.x + q[g * HD + j * 8 + 5] * kc.y
                               + q[g * HD + j * 8 + 6] * kc.z + q[g * HD + j * 8 + 7] * kc.w;
                    }
                }
            } else {
                #pragma unroll
                for (int j = 0; j < 16; ++j) {
                    const float4 ka = *(const float4*)(kb + j * 128);
                    const float4 kc = *(const float4*)(kb + j * 128 + 4);
                    #pragma unroll
                    for (int g = 0; g < NG; ++g) {
                        sc[g] += q[g * HD + j * 8 + 0] * ka.x + q[g * HD + j * 8 + 1] * ka.y
                               + q[g * HD + j * 8 + 2] * ka.z + q[g * HD + j * 8 + 3] * ka.w
                               + q[g * HD + j * 8 + 4] * kc.x + q[g * HD + j * 8 + 5] * kc.y
                               + q[g * HD + j * 8 + 6] * kc.z + q[g * HD + j * 8 + 7] * kc.w;
                    }
                }
            }

            // new-token K correction: token ctx-1's key comes from the `key` input
            if (t == ctx - 1) {
                const float4* kn4 = (const float4*)(key + ((size_t)s * KVH + kvh) * HD);
                float ns[NG] = {0.f, 0.f, 0.f, 0.f};
                #pragma unroll
                for (int c = 0; c < 32; ++c) {
                    const float4 k4 = kn4[c];
                    #pragma unroll
                    for (int g = 0; g < NG; ++g) {
                        ns[g] += q[g * HD + c * 4 + 0] * k4.x + q[g * HD + c * 4 + 1] * k4.y
                               + q[g * HD + c * 4 + 2] * k4.z + q[g * HD + c * 4 + 3] * k4.w;
                    }
                }
                #pragma unroll
                for (int g = 0; g < NG; ++g) sc[g] = ns[g];
            }

            float mv;
            if (t < ctx) {
                #pragma unroll
                for (int g = 0; g < NG; ++g) sc[g] *= SCALE_F;
                mv = fmaxf(fmaxf(sc[0], sc[1]), fmaxf(sc[2], sc[3]));
            } else {
                #pragma unroll
                for (int g = 0; g < NG; ++g) sc[g] = -1e30f;
                mv = -1e30f;
            }

            #pragma unroll
            for (int o = 32; o; o >>= 1) mv = fmaxf(mv, __shfl_xor(mv, o));
            m_w = mv;

            float pr[NG];
            #pragma unroll
            for (int g = 0; g < NG; ++g) {
                pr[g] = __expf(sc[g] - m_w);
                p_lds[wv][g][lane] = pr[g];
                l_w[g] = pr[g];
            }
            #pragma unroll
            for (int o = 32; o; o >>= 1) {
                l_w[0] += __shfl_xor(l_w[0], o);
                l_w[1] += __shfl_xor(l_w[1], o);
                l_w[2] += __shfl_xor(l_w[2], o);
                l_w[3] += __shfl_xor(l_w[3], o);
            }
        }

        if (lane == 0) {
            ml_lds[wv][0] = m_w;
            #pragma unroll
            for (int g = 0; g < NG; ++g) ml_lds[wv][1 + g] = l_w[g];
        }

        // ---- PV: contiguous 1KB V loads, nt variant for ntp items ----
        if (wact) {
            int btv[4];
            #pragma unroll
            for (int b = 0; b < 4; ++b)
                btv[b] = block_tables[s * MAXB + (tw0 >> 4) + b];  // uniform, in-bounds

            const int tl = ctx - 1 - tw0;
            const int tq = lane & 3;          // token-quad within block
            const int dl = lane >> 2;         // d sub-index 0..15

            float acc[NG][8];
            #pragma unroll
            for (int g = 0; g < NG; ++g)
                #pragma unroll
                for (int sub = 0; sub < 8; ++sub) acc[g][sub] = 0.f;

            #pragma unroll
            for (int b = 0; b < 4; ++b) {
                if (tw0 + b * 16 < ctx) {     // skip fully-masked blocks
                    const float* vb = value_cache + (size_t)btv[b] * (KVH * HD * BS)
                                                  + (size_t)kvh * (HD * BS);
                    float4 p4[NG];
                    #pragma unroll
                    for (int g = 0; g < NG; ++g)
                        p4[g] = *(const float4*)&p_lds[wv][g][b * 16 + tq * 4];
                    if (ntp) {
                        #pragma unroll
                        for (int sub = 0; sub < 8; ++sub) {
                            const float4 v4 = ldnt4f(vb + sub * 256 + lane * 4);
                            #pragma unroll
                            for (int g = 0; g < NG; ++g)
                                acc[g][sub] += p4[g].x * v4.x + p4[g].y * v4.y
                                             + p4[g].z * v4.z + p4[g].w * v4.w;
                        }
                    } else {
                        #pragma unroll
                        for (int sub = 0; sub < 8; ++sub) {
                            const float4 v4 = *(const float4*)(vb + sub * 256 + lane * 4);
                            #pragma unroll
                            for (int g = 0; g < NG; ++g)
                                acc[g][sub] += p4[g].x * v4.x + p4[g].y * v4.y
                                             + p4[g].z * v4.z + p4[g].w * v4.w;
                        }
                    }
                }
            }

            // reduce the 4 token-quad groups
            #pragma unroll
            for (int g = 0; g < NG; ++g)
                #pragma unroll
                for (int sub = 0; sub < 8; ++sub) {
                    float a = acc[g][sub];
                    a += __shfl_xor(a, 1);
                    a += __shfl_xor(a, 2);
                    acc[g][sub] = a;
                }

            // new-token V correction (post-reduce; all 4 copies stay identical)
            if (tl >= 0 && tl < WPT) {
                const int btn = block_tables[s * MAXB + ((ctx - 1) >> 4)];
                const float* vbn = value_cache + (size_t)btn * (KVH * HD * BS)
                                               + (size_t)kvh * (HD * BS) + ((ctx - 1) & 15);
                const float* vrow = value + ((size_t)s * KVH + kvh) * HD;
                #pragma unroll
                for (int sub = 0; sub < 8; ++sub) {
                    const int d = sub * 16 + dl;
                    const float dv = vrow[d] - vbn[d * BS];
                    #pragma unroll
                    for (int g = 0; g < NG; ++g)
                        acc[g][sub] += p_lds[wv][g][tl] * dv;
                }
            }

            if (tq == 0) {
                #pragma unroll
                for (int g = 0; g < NG; ++g)
                    #pragma unroll
                    for (int sub = 0; sub < 8; ++sub)
                        o_lds[wv][g * HD + sub * 16 + dl] = acc[g][sub];
            }
        } else {
            #pragma unroll
            for (int i = 0; i < 8; ++i) o_lds[wv][i * 64 + lane] = 0.f;
        }

        __syncthreads();   // merge the 4 wave records

        const float m0 = ml_lds[0][0], m1 = ml_lds[1][0], m2 = ml_lds[2][0], m3 = ml_lds[3][0];
        const float M  = fmaxf(fmaxf(m0, m1), fmaxf(m2, m3));
        const float w0 = __expf(m0 - M), w1 = __expf(m1 - M);
        const float w2 = __expf(m2 - M), w3 = __expf(m3 - M);

        float* rec = ws + (size_t)item * PSTRIDE;
        #pragma unroll
        for (int r = 0; r < 2; ++r) {
            const int idx = tid + r * 256;
            rec[idx] = w0 * o_lds[0][idx] + w1 * o_lds[1][idx]
                     + w2 * o_lds[2][idx] + w3 * o_lds[3][idx];
        }
        if (tid < NG) {
            rec[512 + tid] = w0 * ml_lds[0][1 + tid] + w1 * ml_lds[1][1 + tid]
                           + w2 * ml_lds[2][1 + tid] + w3 * ml_lds[3][1 + tid];
        }
        if (tid == 4) rec[516] = M;
        // next grab's B1 separates this item's o_lds reads from the next item's writes
    }
}

// Kernel 2: LSE-combine partitions -> output. One (seq, kvh, g) per block.
__global__ __launch_bounds__(128) void pa_reduce_kernel(
    const float* __restrict__ ws,
    const int*   __restrict__ context_lens,
    float*       __restrict__ out)
{
    const int b    = blockIdx.x;        // ((s*KVH)+kvh)*NG + g
    const int g    = b & 3;
    const int pair = b >> 2;            // s*KVH + kvh
    const int s    = pair >> 3;
    const int kvh  = pair & 7;
    const int ctx  = context_lens[s];
    const int np   = (ctx + PART - 1) / PART;

    const int d = threadIdx.x;
    const float* base = ws + (size_t)pair * NPART * PSTRIDE;

    float M = -1e30f;
    for (int p2 = 0; p2 < np; ++p2) M = fmaxf(M, base[p2 * PSTRIDE + 516]);

    float L = 0.f, acc = 0.f;
    for (int p2 = 0; p2 < np; ++p2) {
        const float* rec = base + p2 * PSTRIDE;
        const float w = __expf(rec[516] - M);
        L   += w * rec[512 + g];
        acc += w * rec[g * HD + d];
    }

    out[(size_t)s * (KVH * NG * HD) + (size_t)(kvh * NG + g) * HD + d] = acc / L;
}

extern "C" void kernel_launch(void* const* d_in, const int* in_sizes, int n_in,
                              void* d_out, int out_size, void* d_ws, size_t ws_size,
                              hipStream_t stream) {
    const float* query       = (const float*)d_in[0];
    const float* key         = (const float*)d_in[1];
    const float* value       = (const float*)d_in[2];
    const float* key_cache   = (const float*)d_in[3];
    const float* value_cache = (const float*)d_in[4];
    const int*   block_tables  = (const int*)d_in[5];
    const int*   context_lens  = (const int*)d_in[6];
    // d_in[7] slot_mapping unused: slot is derivable from context_lens + block_tables

    float* out = (float*)d_out;
    float* ws  = (float*)d_ws;   // records: 2048*520*4 = 4.26 MB, + 4 B counter
    unsigned int* counter = (unsigned int*)((char*)d_ws + REC_BYTES);

    (void)hipMemsetAsync(counter, 0, sizeof(unsigned int), stream);
    pa_partial_kernel<<<NWORKERS, 256, 0, stream>>>(
        query, key, value, key_cache, value_cache, block_tables, context_lens, ws, counter);
    pa_reduce_kernel<<<NSEQ * KVH * NG, 128, 0, stream>>>(ws, context_lens, out);
}